// Round 2
// baseline (554.216 us; speedup 1.0000x reference)
//
#include <hip/hip_runtime.h>
#include <hip/hip_bf16.h>
#include <stdint.h>

// VectorQuantization: out[n] = codebook[argmax_k dot(x[n], codebook[k])]
// (L2-normalize is a positive row-scalar -> argmax-invariant -> skipped)
//
// Pipeline:
//  1) split_hi_lo: fp32 -> (bf16 hi, bf16 lo) for x and codebook (in d_ws)
//  2) vq_argmax: 128x128-tile MFMA GEMM (3 passes hi*hi + hi*lo + lo*hi ->
//     fp32-accurate sims) with fused per-row argmax epilogue; partials to ws
//  3) reduce_gather: reduce NSPLIT partials per row, gather codebook row
//
// R2 changes vs R1 (488 us, MfmaUtil 38%, occupancy 23%, 3.35e7 bank-conflict cyc):
//  - __launch_bounds__(256,3): force allocator under ~170 total VGPR+AGPR
//    -> 3 blocks/CU instead of 2 (LDS 34KB allows 4; regs were the limiter)
//  - XOR-swizzled LDS chunk placement: logical chunk (row,kc) stored at slot
//    row*4 + (kc ^ ((row>>1)&3)). Staging permutes only within each 64B
//    global row (coalescing preserved, global_load_lds lane-contiguous dest
//    preserved); frag reads now spread 16-lane phases across all 8 bank
//    groups (2 lanes/group = conflict-free) instead of 2 groups (8-way).

typedef __bf16 bf16x8 __attribute__((ext_vector_type(8)));
typedef float f32x4 __attribute__((ext_vector_type(4)));

#define M_ROWS 8192
#define DIM 512
#define K_CODES 16384
#define BM 128
#define BN 128
#define BK 32
#define NSPLIT 16
#define NTILES ((K_CODES / NSPLIT) / BN) /* 8 */
#define NEG_INF (-3.402823466e+38f)

typedef __attribute__((address_space(1))) uint32_t as1_u32;
typedef __attribute__((address_space(3))) uint32_t as3_u32;

__device__ __forceinline__ void gll16(const void* g, void* l) {
  // async global->LDS, 16B/lane; LDS dest = wave-uniform base + lane*16
  __builtin_amdgcn_global_load_lds((const as1_u32*)(uintptr_t)g,
                                   (as3_u32*)(uintptr_t)l, 16, 0, 0);
}

// stage a [128 rows x 32 cols] bf16 tile (8 KB) from row-major [*, DIM] source
// into swizzled LDS layout: slot s holds logical chunk (row=s>>2, kc=(s&3)^((row>>1)&3)).
__device__ __forceinline__ void stage_tile(const __bf16* __restrict__ g_base,
                                           __bf16* lds_tile, int tid) {
#pragma unroll
  for (int r = 0; r < 2; ++r) {
    const int s = r * 256 + tid;        // LDS 16B-slot id
    const int row = s >> 2;
    const int kc = (s & 3) ^ ((row >> 1) & 3);   // swizzled k-chunk to fetch
    const __bf16* g = g_base + (size_t)row * DIM + (kc << 3);
    // wave-uniform LDS base: slot of this wave's lane 0, in elements
    __bf16* l = lds_tile + ((size_t)(r * 256 + (tid & 192)) << 3);
    gll16((const void*)g, (void*)l);
  }
}

__global__ void split_hi_lo(const float* __restrict__ src, __bf16* __restrict__ hi,
                            __bf16* __restrict__ lo, int n4) {
  int i = blockIdx.x * 256 + threadIdx.x;
  if (i >= n4) return;
  const float4 v = reinterpret_cast<const float4*>(src)[i];
  float f[4] = {v.x, v.y, v.z, v.w};
  unsigned short hb[4], lb[4];
#pragma unroll
  for (int j = 0; j < 4; ++j) {
    __bf16 h = (__bf16)f[j];
    __bf16 l = (__bf16)(f[j] - (float)h);
    hb[j] = __builtin_bit_cast(unsigned short, h);
    lb[j] = __builtin_bit_cast(unsigned short, l);
  }
  reinterpret_cast<ushort4*>(hi)[i] = make_ushort4(hb[0], hb[1], hb[2], hb[3]);
  reinterpret_cast<ushort4*>(lo)[i] = make_ushort4(lb[0], lb[1], lb[2], lb[3]);
}

__global__ __launch_bounds__(256, 3) void vq_argmax(
    const __bf16* __restrict__ xh, const __bf16* __restrict__ xl,
    const __bf16* __restrict__ ch, const __bf16* __restrict__ cl,
    float* __restrict__ part_v, int* __restrict__ part_i) {
  __shared__ __bf16 sxh[BM * BK];
  __shared__ __bf16 sxl[BM * BK];
  __shared__ __bf16 sch[BN * BK];
  __shared__ __bf16 scl[BN * BK];
  __shared__ float red_v[2][BM];
  __shared__ int red_i[2][BM];

  const int tid = threadIdx.x;
  const int w = tid >> 6, lane = tid & 63;
  const int wm = w & 1, wn = w >> 1;        // 2x2 wave grid over 128x128 tile
  const int l15 = lane & 15, quad = lane >> 4;
  const int row0 = blockIdx.x * BM;
  const int split = blockIdx.y;
  const int n_split = split * (K_CODES / NSPLIT);
  // swizzled k-chunk element offset for this lane's fragment reads
  const int kq = ((quad ^ ((l15 >> 1) & 3)) << 3);

  float bv[4][4];
  int bi[4][4];
#pragma unroll
  for (int i = 0; i < 4; ++i)
#pragma unroll
    for (int r = 0; r < 4; ++r) {
      bv[i][r] = NEG_INF;
      bi[i][r] = 0x7fffffff;
    }

#pragma unroll 1
  for (int nt = 0; nt < NTILES; ++nt) {
    const int n0 = n_split + nt * BN;
    f32x4 acc[4][4];
#pragma unroll
    for (int i = 0; i < 4; ++i)
#pragma unroll
      for (int j = 0; j < 4; ++j) acc[i][j] = (f32x4){0.f, 0.f, 0.f, 0.f};

#pragma unroll 1
    for (int ks = 0; ks < DIM / BK; ++ks) {
      const int k0 = ks * BK;
      stage_tile(xh + (size_t)row0 * DIM + k0, sxh, tid);
      stage_tile(xl + (size_t)row0 * DIM + k0, sxl, tid);
      stage_tile(ch + (size_t)n0 * DIM + k0, sch, tid);
      stage_tile(cl + (size_t)n0 * DIM + k0, scl, tid);
      __syncthreads();  // compiler drains vmcnt before s_barrier

      bf16x8 Ah[4], Al[4], Bh[4], Bl[4];
#pragma unroll
      for (int i = 0; i < 4; ++i) {
        // A frag: m = lane&15, k = quad*8 + j; swizzled slot = row*4 + (quad^sw)
        Ah[i] = *(const bf16x8*)&sxh[(wm * 64 + i * 16 + l15) * BK + kq];
        Al[i] = *(const bf16x8*)&sxl[(wm * 64 + i * 16 + l15) * BK + kq];
        Bh[i] = *(const bf16x8*)&sch[(wn * 64 + i * 16 + l15) * BK + kq];
        Bl[i] = *(const bf16x8*)&scl[(wn * 64 + i * 16 + l15) * BK + kq];
      }
#pragma unroll
      for (int i = 0; i < 4; ++i)
#pragma unroll
        for (int j = 0; j < 4; ++j) {
          acc[i][j] = __builtin_amdgcn_mfma_f32_16x16x32_bf16(Ah[i], Bh[j], acc[i][j], 0, 0, 0);
          acc[i][j] = __builtin_amdgcn_mfma_f32_16x16x32_bf16(Ah[i], Bl[j], acc[i][j], 0, 0, 0);
          acc[i][j] = __builtin_amdgcn_mfma_f32_16x16x32_bf16(Al[i], Bh[j], acc[i][j], 0, 0, 0);
        }
      __syncthreads();
    }

    // fused argmax epilogue over this 128-col tile
    // C/D layout: row = i*16 + quad*4 + reg, col = j*16 + (lane&15)
#pragma unroll
    for (int i = 0; i < 4; ++i)
#pragma unroll
      for (int r = 0; r < 4; ++r) {
        float v = NEG_INF;
        int ci = 0x7fffffff;
#pragma unroll
        for (int j = 0; j < 4; ++j) {
          float s = acc[i][j][r];
          int c = n0 + wn * 64 + j * 16 + l15;
          if (s > v) { v = s; ci = c; }  // strict > keeps lowest col on tie
        }
        // butterfly across the 16 lanes of this quad (cols)
#pragma unroll
        for (int d = 1; d < 16; d <<= 1) {
          float ov = __shfl_xor(v, d);
          int oi = __shfl_xor(ci, d);
          if (ov > v || (ov == v && oi < ci)) { v = ov; ci = oi; }
        }
        if (v > bv[i][r] || (v == bv[i][r] && ci < bi[i][r])) {
          bv[i][r] = v;
          bi[i][r] = ci;
        }
      }
  }

  // combine the two column-halves (wn=0,1) per row, write per-block partial
  if (l15 == 0) {
#pragma unroll
    for (int i = 0; i < 4; ++i)
#pragma unroll
      for (int r = 0; r < 4; ++r) {
        const int rl = wm * 64 + i * 16 + quad * 4 + r;
        red_v[wn][rl] = bv[i][r];
        red_i[wn][rl] = bi[i][r];
      }
  }
  __syncthreads();
  if (tid < BM) {
    float v0 = red_v[0][tid], v1 = red_v[1][tid];
    int i0 = red_i[0][tid], i1 = red_i[1][tid];
    bool take1 = (v1 > v0) || (v1 == v0 && i1 < i0);
    const size_t o = (size_t)(row0 + tid) * NSPLIT + split;
    part_v[o] = take1 ? v1 : v0;
    part_i[o] = take1 ? i1 : i0;
  }
}

__global__ void reduce_gather(const float* __restrict__ part_v, const int* __restrict__ part_i,
                              const float* __restrict__ cb, float* __restrict__ out) {
  const int row = blockIdx.x;
  const int lane = threadIdx.x;
  float v = NEG_INF;
  int ci = 0x7fffffff;
  if (lane < NSPLIT) {
    v = part_v[(size_t)row * NSPLIT + lane];
    ci = part_i[(size_t)row * NSPLIT + lane];
  }
#pragma unroll
  for (int d = 1; d < NSPLIT; d <<= 1) {
    float ov = __shfl_xor(v, d);
    int oi = __shfl_xor(ci, d);
    if (ov > v || (ov == v && oi < ci)) { v = ov; ci = oi; }
  }
  const int best = __shfl(ci, 0);
  const float4* src = (const float4*)(cb + (size_t)best * DIM);
  float4* dst = (float4*)(out + (size_t)row * DIM);
  dst[lane] = src[lane];        // 512 f32 = 128 float4, 64 lanes x 2
  dst[lane + 64] = src[lane + 64];
}

extern "C" void kernel_launch(void* const* d_in, const int* in_sizes, int n_in,
                              void* d_out, int out_size, void* d_ws, size_t ws_size,
                              hipStream_t stream) {
  const float* x = (const float*)d_in[0];
  const float* cb = (const float*)d_in[1];
  float* out = (float*)d_out;

  // ws layout: x_hi(8MB) x_lo(8MB) c_hi(16MB) c_lo(16MB) part_v(512KB) part_i(512KB)
  __bf16* xh = (__bf16*)d_ws;
  __bf16* xl = xh + (size_t)M_ROWS * DIM;
  __bf16* ch = xl + (size_t)M_ROWS * DIM;
  __bf16* cl = ch + (size_t)K_CODES * DIM;
  float* part_v = (float*)(cl + (size_t)K_CODES * DIM);
  int* part_i = (int*)(part_v + (size_t)M_ROWS * NSPLIT);

  split_hi_lo<<<(M_ROWS * DIM / 4) / 256, 256, 0, stream>>>(x, xh, xl, M_ROWS * DIM / 4);
  split_hi_lo<<<(K_CODES * DIM / 4) / 256, 256, 0, stream>>>(cb, ch, cl, K_CODES * DIM / 4);
  vq_argmax<<<dim3(M_ROWS / BM, NSPLIT), 256, 0, stream>>>(xh, xl, ch, cl, part_v, part_i);
  reduce_gather<<<M_ROWS, 64, 0, stream>>>(part_v, part_i, cb, out);
}

// Round 3
// 311.787 us; speedup vs baseline: 1.7775x; 1.7775x over previous
//
#include <hip/hip_runtime.h>
#include <hip/hip_bf16.h>
#include <stdint.h>

// VectorQuantization: out[n] = codebook[argmax_k dot(x[n], codebook[k])]
// (L2-normalize is a positive row-scalar -> argmax-invariant -> skipped)
//
// R3 strategy: single-pass fp16 MFMA GEMM (3x less MFMA work than R1/R2's
// bf16 hi/lo 3-pass) computing approximate sims (error-diff std ~1.3e-4),
// fused top-2-per-(row,split) epilogue; then a recheck kernel that takes the
// 64 candidates/row (32 splits x top-2), and for any candidate within
// MARGIN=2e-3 (~15 sigma) of the approx max computes an exact fp64 dot from
// the original fp32 inputs; winner (lowest index on tie) -> gather.
//
// Carried from R2: zero-bank-conflict XOR swizzle on LDS chunk placement
// (verified SQ_LDS_BANK_CONFLICT 3.35e7 -> 0).

typedef _Float16 half8 __attribute__((ext_vector_type(8)));
typedef _Float16 half4v __attribute__((ext_vector_type(4)));
typedef float f32x4 __attribute__((ext_vector_type(4)));

#define M_ROWS 8192
#define DIM 512
#define K_CODES 16384
#define BM 128
#define BN 128
#define BK 32
#define NSPLIT 32
#define NT ((K_CODES / NSPLIT) / BN) /* 4 */
#define NEG_INF (-3.402823466e+38f)
#define MARGIN 2.0e-3f

typedef __attribute__((address_space(1))) uint32_t as1_u32;
typedef __attribute__((address_space(3))) uint32_t as3_u32;

__device__ __forceinline__ void gll16(const void* g, void* l) {
  // async global->LDS, 16B/lane; LDS dest = wave-uniform base + lane*16
  __builtin_amdgcn_global_load_lds((const as1_u32*)(uintptr_t)g,
                                   (as3_u32*)(uintptr_t)l, 16, 0, 0);
}

// stage a [128 rows x 32 cols] fp16 tile (8 KB) from row-major [*, DIM] source
// into swizzled LDS layout: slot s holds logical chunk (row=s>>2, kc=(s&3)^((row>>1)&3)).
__device__ __forceinline__ void stage_tile(const _Float16* __restrict__ g_base,
                                           _Float16* lds_tile, int tid) {
#pragma unroll
  for (int r = 0; r < 2; ++r) {
    const int s = r * 256 + tid;        // LDS 16B-slot id
    const int row = s >> 2;
    const int kc = (s & 3) ^ ((row >> 1) & 3);   // swizzled k-chunk to fetch
    const _Float16* g = g_base + (size_t)row * DIM + (kc << 3);
    _Float16* l = lds_tile + ((size_t)(r * 256 + (tid & 192)) << 3);
    gll16((const void*)g, (void*)l);
  }
}

__global__ void to_f16(const float* __restrict__ src, _Float16* __restrict__ dst, int n4) {
  int i = blockIdx.x * 256 + threadIdx.x;
  if (i >= n4) return;
  const float4 v = reinterpret_cast<const float4*>(src)[i];
  half4v h = {(_Float16)v.x, (_Float16)v.y, (_Float16)v.z, (_Float16)v.w};
  reinterpret_cast<half4v*>(dst)[i] = h;
}

__global__ __launch_bounds__(256, 2) void vq_argmax(
    const _Float16* __restrict__ xh, const _Float16* __restrict__ ch,
    float* __restrict__ pv, int* __restrict__ pi) {
  __shared__ _Float16 sxh[BM * BK];
  __shared__ _Float16 sch[BN * BK];
  __shared__ float rv1[2][BM], rv2[2][BM];
  __shared__ int ri1[2][BM], ri2[2][BM];

  const int tid = threadIdx.x;
  const int w = tid >> 6, lane = tid & 63;
  const int wm = w & 1, wn = w >> 1;        // 2x2 wave grid over 128x128 tile
  const int l15 = lane & 15, quad = lane >> 4;
  const int row0 = blockIdx.x * BM;
  const int split = blockIdx.y;
  const int n_base = split * (K_CODES / NSPLIT);
  // swizzled k-chunk element offset for this lane's fragment reads
  const int kq = ((quad ^ ((l15 >> 1) & 3)) << 3);

  float bv1[4][4], bv2[4][4];
  int bi1[4][4], bi2[4][4];
#pragma unroll
  for (int i = 0; i < 4; ++i)
#pragma unroll
    for (int r = 0; r < 4; ++r) {
      bv1[i][r] = NEG_INF; bv2[i][r] = NEG_INF;
      bi1[i][r] = 0x7fffffff; bi2[i][r] = 0x7fffffff;
    }

#pragma unroll 1
  for (int nt = 0; nt < NT; ++nt) {
    const int n0 = n_base + nt * BN;
    f32x4 acc[4][4];
#pragma unroll
    for (int i = 0; i < 4; ++i)
#pragma unroll
      for (int j = 0; j < 4; ++j) acc[i][j] = (f32x4){0.f, 0.f, 0.f, 0.f};

#pragma unroll 1
    for (int ks = 0; ks < DIM / BK; ++ks) {
      const int k0 = ks * BK;
      stage_tile(xh + (size_t)row0 * DIM + k0, sxh, tid);
      stage_tile(ch + (size_t)n0 * DIM + k0, sch, tid);
      __syncthreads();

      half8 A[4], B[4];
#pragma unroll
      for (int i = 0; i < 4; ++i) {
        // A frag: m = lane&15, k = quad*8 + j; swizzled slot = row*4 + (quad^sw)
        A[i] = *(const half8*)&sxh[(wm * 64 + i * 16 + l15) * BK + kq];
        B[i] = *(const half8*)&sch[(wn * 64 + i * 16 + l15) * BK + kq];
      }
#pragma unroll
      for (int i = 0; i < 4; ++i)
#pragma unroll
        for (int j = 0; j < 4; ++j)
          acc[i][j] = __builtin_amdgcn_mfma_f32_16x16x32_f16(A[i], B[j], acc[i][j], 0, 0, 0);
      __syncthreads();
    }

    // update per-lane running top-2 (candidates arrive in ascending index order,
    // so strict > keeps the lowest index at each rank)
    // C/D layout: row = i*16 + quad*4 + r, col = j*16 + (lane&15)
#pragma unroll
    for (int i = 0; i < 4; ++i)
#pragma unroll
      for (int r = 0; r < 4; ++r)
#pragma unroll
        for (int j = 0; j < 4; ++j) {
          float s = acc[i][j][r];
          int c = n0 + wn * 64 + j * 16 + l15;
          if (s > bv1[i][r]) {
            bv2[i][r] = bv1[i][r]; bi2[i][r] = bi1[i][r];
            bv1[i][r] = s; bi1[i][r] = c;
          } else if (s > bv2[i][r]) {
            bv2[i][r] = s; bi2[i][r] = c;
          }
        }
  }

  // butterfly-merge top-2 across the 16 lanes (columns) of each quad
#pragma unroll
  for (int i = 0; i < 4; ++i)
#pragma unroll
    for (int r = 0; r < 4; ++r) {
      float a1 = bv1[i][r], a2 = bv2[i][r];
      int x1 = bi1[i][r], x2 = bi2[i][r];
#pragma unroll
      for (int d = 1; d < 16; d <<= 1) {
        float b1 = __shfl_xor(a1, d), b2 = __shfl_xor(a2, d);
        int y1 = __shfl_xor(x1, d), y2 = __shfl_xor(x2, d);
        bool bw = (b1 > a1) || (b1 == a1 && y1 < x1);
        float w1 = bw ? b1 : a1;  int wi = bw ? y1 : x1;
        float l1 = bw ? a1 : b1;  int li = bw ? x1 : y1;
        float s2 = bw ? b2 : a2;  int si = bw ? y2 : x2;
        bool t = (s2 > l1) || (s2 == l1 && si < li);
        a1 = w1; x1 = wi;
        a2 = t ? s2 : l1; x2 = t ? si : li;
      }
      bv1[i][r] = a1; bi1[i][r] = x1; bv2[i][r] = a2; bi2[i][r] = x2;
    }

  if (l15 == 0) {
#pragma unroll
    for (int i = 0; i < 4; ++i)
#pragma unroll
      for (int r = 0; r < 4; ++r) {
        const int rl = wm * 64 + i * 16 + quad * 4 + r;
        rv1[wn][rl] = bv1[i][r]; ri1[wn][rl] = bi1[i][r];
        rv2[wn][rl] = bv2[i][r]; ri2[wn][rl] = bi2[i][r];
      }
  }
  __syncthreads();
  if (tid < BM) {
    float a1 = rv1[0][tid], a2 = rv2[0][tid];
    int x1 = ri1[0][tid], x2 = ri2[0][tid];
    float b1 = rv1[1][tid], b2 = rv2[1][tid];
    int y1 = ri1[1][tid], y2 = ri2[1][tid];
    bool bw = (b1 > a1) || (b1 == a1 && y1 < x1);
    float w1 = bw ? b1 : a1;  int wi = bw ? y1 : x1;
    float l1 = bw ? a1 : b1;  int li = bw ? x1 : y1;
    float s2 = bw ? b2 : a2;  int si = bw ? y2 : x2;
    bool t = (s2 > l1) || (s2 == l1 && si < li);
    float m2 = t ? s2 : l1;  int mi2 = t ? si : li;
    // partial layout: [row][split*2 + rank]
    const size_t o = (size_t)(row0 + tid) * (NSPLIT * 2) + split * 2;
    pv[o] = w1; pi[o] = wi;
    pv[o + 1] = m2; pi[o + 1] = mi2;
  }
}

__global__ void recheck_gather(const float* __restrict__ pv, const int* __restrict__ pi,
                               const float* __restrict__ x, const float* __restrict__ cb,
                               float* __restrict__ out) {
  const int row = blockIdx.x;
  const int lane = threadIdx.x;   // 64 lanes = 32 splits x top-2
  float v = pv[(size_t)row * 64 + lane];
  int ci = pi[(size_t)row * 64 + lane];

  // wave max with lowest-index tie-break
  float m1 = v; int mi1 = ci;
#pragma unroll
  for (int d = 1; d < 64; d <<= 1) {
    float ov = __shfl_xor(m1, d);
    int oi = __shfl_xor(mi1, d);
    if (ov > m1 || (ov == m1 && oi < mi1)) { m1 = ov; mi1 = oi; }
  }

  const bool flag = (v >= m1 - MARGIN);
  const unsigned long long mask = __ballot(flag);
  int winner;
  if (__popcll(mask) == 1) {
    winner = mi1;   // approx winner is >=15-sigma clear of every other candidate
  } else {
    // exact fp64 dot from original fp32 inputs for each flagged candidate
    double e = -1.0e300;
    if (flag) {
      const float* xr = x + (size_t)row * DIM;
      const float* cr = cb + (size_t)ci * DIM;
      double s = 0.0;
#pragma unroll 4
      for (int t = 0; t < DIM; t += 4) {
        const float4 a = *(const float4*)(xr + t);
        const float4 b = *(const float4*)(cr + t);
        s += (double)a.x * b.x + (double)a.y * b.y + (double)a.z * b.z + (double)a.w * b.w;
      }
      e = s;
    }
    int ei = flag ? ci : 0x7fffffff;
#pragma unroll
    for (int d = 1; d < 64; d <<= 1) {
      double oe = __shfl_xor(e, d);
      int oi = __shfl_xor(ei, d);
      if (oe > e || (oe == e && oi < ei)) { e = oe; ei = oi; }
    }
    winner = ei;
  }

  const float4* src = (const float4*)(cb + (size_t)winner * DIM);
  float4* dst = (float4*)(out + (size_t)row * DIM);
  dst[lane] = src[lane];         // 512 f32 = 128 float4, 64 lanes x 2
  dst[lane + 64] = src[lane + 64];
}

extern "C" void kernel_launch(void* const* d_in, const int* in_sizes, int n_in,
                              void* d_out, int out_size, void* d_ws, size_t ws_size,
                              hipStream_t stream) {
  const float* x = (const float*)d_in[0];
  const float* cb = (const float*)d_in[1];
  float* out = (float*)d_out;

  // ws layout: x_f16(8MB) c_f16(16MB) pv(2MB) pi(2MB)
  _Float16* xh = (_Float16*)d_ws;
  _Float16* ch = xh + (size_t)M_ROWS * DIM;
  float* pv = (float*)(ch + (size_t)K_CODES * DIM);
  int* pi = (int*)(pv + (size_t)M_ROWS * NSPLIT * 2);

  to_f16<<<(M_ROWS * DIM / 4) / 256, 256, 0, stream>>>(x, xh, M_ROWS * DIM / 4);
  to_f16<<<(K_CODES * DIM / 4) / 256, 256, 0, stream>>>(cb, ch, K_CODES * DIM / 4);
  vq_argmax<<<dim3(M_ROWS / BM, NSPLIT), 256, 0, stream>>>(xh, ch, pv, pi);
  recheck_gather<<<M_ROWS, 64, 0, stream>>>(pv, pi, x, cb, out);
}